// Round 1
// baseline (463.902 us; speedup 1.0000x reference)
//
#include <hip/hip_runtime.h>
#include <hip/hip_bf16.h>

// Problem constants (match reference): K=4, B=4096, T=32, D=128
constexpr int K = 4;
constexpr int B = 4096;   // power of two: kb>>12 = k, kb&4095 = b
constexpr int T = 32;
constexpr int D = 128;
constexpr int TT = T * T;   // 1024 pairs per anchor
constexpr int TD = T * D;   // 4096 floats per anchor's nbr_embed

// ext_vector_type is a true clang vector type -> legal operand for
// __builtin_nontemporal_store (HIP's float4 struct is not).
typedef float f4 __attribute__((ext_vector_type(4)));

__global__ __launch_bounds__(256) void distance_layer_kernel(
    const float* __restrict__ semb,     // [K,B,D]
    const int*   __restrict__ slabels,  // [K,B]
    const int*   __restrict__ topk,     // [K,B,T]
    float* __restrict__ pos,            // [K,B,T,T]
    float* __restrict__ neg,            // [K,B,T,T]
    float* __restrict__ maskf,          // [K,B,T,T] (bool as 0.0/1.0)
    float* __restrict__ nbr)            // [K,B,T,D]
{
    const int kb  = blockIdx.x;        // k*B + b
    const int k   = kb >> 12;
    const int tid = threadIdx.x;

    __shared__ f4    anchor4[D / 4];   // 32 x float4 = anchor embedding row
    __shared__ int   idx_s[T];
    __shared__ float nsim_s[T];
    __shared__ int   same_s[T];

    // ---- Phase 0: stage indices, labels, anchor row -------------------
    const int my_label = slabels[kb];
    if (tid < T) {
        const int idx = topk[(size_t)kb * T + tid];
        idx_s[tid]  = idx;
        same_s[tid] = (slabels[k * B + idx] == my_label) ? 1 : 0;
    }
    if (tid < D / 4) {
        anchor4[tid] =
            reinterpret_cast<const f4*>(semb + (size_t)kb * D)[tid];
    }
    __syncthreads();

    // ---- Phase A: gather nbr_embed + nsim dot products ----------------
    // chunk c in [0,1024): row t = c>>5, float4-within-row d4 = c&31.
    // Per j, a wave's 64 lanes cover two full rows -> 512B contiguous
    // gather-read per half-wave, 1KB contiguous streaming write per wave.
    const f4* semb4 = reinterpret_cast<const f4*>(semb + (size_t)k * B * D);
    f4*       nbr4  = reinterpret_cast<f4*>(nbr + (size_t)kb * TD);

    #pragma unroll
    for (int j = 0; j < 4; ++j) {
        const int c  = tid + 256 * j;
        const int t  = c >> 5;
        const int d4 = c & 31;
        const f4 a = anchor4[d4];
        const f4 s = semb4[(size_t)idx_s[t] * (D / 4) + d4];
        __builtin_nontemporal_store(s, nbr4 + c);
        float p = a.x * s.x + a.y * s.y + a.z * s.z + a.w * s.w;
        // reduce across the 32 lanes sharing t (xor<=16 stays in-half)
        #pragma unroll
        for (int m = 16; m >= 1; m >>= 1)
            p += __shfl_xor(p, m, 64);
        if ((tid & 31) == 0) nsim_s[t] = p;
    }
    __syncthreads();

    // ---- Phase B: 1024 (s,d) pairs, 4 per thread as one float4 --------
    f4* pos4  = reinterpret_cast<f4*>(pos   + (size_t)kb * TT);
    f4* neg4  = reinterpret_cast<f4*>(neg   + (size_t)kb * TT);
    f4* mask4 = reinterpret_cast<f4*>(maskf + (size_t)kb * TT);

    const int s_row = tid >> 3;        // (4*tid)>>5
    const int d0    = (tid & 7) * 4;   // (4*tid)&31
    const int   ss = same_s[s_row];
    const float ps = nsim_s[s_row];

    f4 pv, nv, mv;
    {
        const int m0 = ss & (same_s[d0 + 0] ^ 1);
        const int m1 = ss & (same_s[d0 + 1] ^ 1);
        const int m2 = ss & (same_s[d0 + 2] ^ 1);
        const int m3 = ss & (same_s[d0 + 3] ^ 1);
        pv.x = m0 ? ps : 0.0f;  nv.x = m0 ? nsim_s[d0 + 0] : 0.0f;  mv.x = (float)m0;
        pv.y = m1 ? ps : 0.0f;  nv.y = m1 ? nsim_s[d0 + 1] : 0.0f;  mv.y = (float)m1;
        pv.z = m2 ? ps : 0.0f;  nv.z = m2 ? nsim_s[d0 + 2] : 0.0f;  mv.z = (float)m2;
        pv.w = m3 ? ps : 0.0f;  nv.w = m3 ? nsim_s[d0 + 3] : 0.0f;  mv.w = (float)m3;
    }
    __builtin_nontemporal_store(pv, pos4  + tid);
    __builtin_nontemporal_store(nv, neg4  + tid);
    __builtin_nontemporal_store(mv, mask4 + tid);
}

extern "C" void kernel_launch(void* const* d_in, const int* in_sizes, int n_in,
                              void* d_out, int out_size, void* d_ws, size_t ws_size,
                              hipStream_t stream) {
    const float* semb    = (const float*)d_in[0];
    const int*   slabels = (const int*)d_in[1];
    const int*   topk    = (const int*)d_in[2];

    float* out = (float*)d_out;
    const size_t KBTT = (size_t)K * B * T * T;   // 16,777,216
    float* pos   = out;
    float* neg   = out + KBTT;
    float* maskf = out + 2 * KBTT;
    float* nbr   = out + 3 * KBTT;

    distance_layer_kernel<<<dim3(K * B), dim3(256), 0, stream>>>(
        semb, slabels, topk, pos, neg, maskf, nbr);
}